// Round 1
// baseline (2998.985 us; speedup 1.0000x reference)
//
#include <hip/hip_runtime.h>
#include <hip/hip_bf16.h>
#include <stdint.h>

typedef __bf16 bf16x8 __attribute__((ext_vector_type(8)));
typedef float  f32x4  __attribute__((ext_vector_type(4)));
typedef short  short8v __attribute__((ext_vector_type(8)));

// ---------------- async global->LDS (wave-uniform LDS base + lane*16) -------
__device__ __forceinline__ void gload16(const void* gp, void* lp) {
  __builtin_amdgcn_global_load_lds(
      reinterpret_cast<const __attribute__((address_space(1))) uint32_t*>(
          reinterpret_cast<uintptr_t>(gp)),
      reinterpret_cast<__attribute__((address_space(3))) uint32_t*>(
          (uintptr_t)(uint32_t)reinterpret_cast<uintptr_t>(lp)),
      16, 0, 0);
}

// ---------------- octahedral group tables (replicates numpy enumeration) ----
__global__ void build_tables(int* __restrict__ shift, int* __restrict__ rot) {
  if (threadIdx.x != 0 || blockIdx.x != 0) return;
  const int perms[6][3] = {{0,1,2},{0,2,1},{1,0,2},{1,2,0},{2,0,1},{2,1,0}};
  const int psign[6] = {1,-1,-1,1,1,-1};
  int mats[24][3][3];
  int nm = 0;
  for (int pi = 0; pi < 6; ++pi)
    for (int sb = 0; sb < 8; ++sb) {
      int s0 = (sb&4)?-1:1, s1 = (sb&2)?-1:1, s2 = (sb&1)?-1:1;
      if (psign[pi]*s0*s1*s2 != 1) continue;
      int sg[3] = {s0,s1,s2};
      for (int i = 0; i < 3; ++i)
        for (int j = 0; j < 3; ++j)
          mats[nm][i][j] = (j == perms[pi][i]) ? sg[i] : 0;
      ++nm;
    }
  // SHIFT[g][h] = index of mats[g]^T @ mats[h]
  for (int g = 0; g < 24; ++g)
    for (int h = 0; h < 24; ++h) {
      int P[3][3];
      for (int i = 0; i < 3; ++i)
        for (int j = 0; j < 3; ++j) {
          int v = 0;
          for (int k = 0; k < 3; ++k) v += mats[g][k][i]*mats[h][k][j];
          P[i][j] = v;
        }
      int id = -1;
      for (int m = 0; m < 24 && id < 0; ++m) {
        bool eq = true;
        for (int i = 0; i < 3; ++i)
          for (int j = 0; j < 3; ++j) eq = eq && (mats[m][i][j] == P[i][j]);
        if (eq) id = m;
      }
      shift[g*24 + h] = id;
    }
  // ROT[g][dst] = src flat index: src_j = sum_i (v_i-1)*M[i][j] + 1
  for (int g = 0; g < 24; ++g)
    for (int z = 0; z < 3; ++z)
      for (int y = 0; y < 3; ++y)
        for (int x = 0; x < 3; ++x) {
          int v[3] = {z-1, y-1, x-1}, s[3];
          for (int j = 0; j < 3; ++j) {
            int a = 0;
            for (int i = 0; i < 3; ++i) a += v[i]*mats[g][i][j];
            s[j] = a + 1;
          }
          rot[g*27 + (z*3+y)*3 + x] = (s[0]*3 + s[1])*3 + s[2];
        }
}

// ---------------- weight fold: cw[oc][s][icf] bf16 --------------------------
__global__ void prep_weights(const float* __restrict__ w, const float* __restrict__ rw,
                             const int* __restrict__ shift, const int* __restrict__ rot,
                             __hip_bfloat16* __restrict__ cw) {
  int idx = blockIdx.x*256 + threadIdx.x;
  if (idx >= 384*27*384) return;
  int icf = idx % 384;
  int s   = (idx / 384) % 27;
  int oc  = idx / (384*27);
  int i = icf / 24, h = icf - i*24;
  int o = oc  / 24, g = oc  - o*24;
  int gg = shift[g*24 + h];
  int ss = rot[g*27 + s];
  float v = rw[g]      * w[((o*16 + i)*24 + gg)*27 + ss]
          + rw[24 + g] * w[(((16 + o)*16 + i)*24 + gg)*27 + ss];
  cw[idx] = __float2bfloat16(v);
}

// ---------------- x (NCDHW fp32) -> padded NDHWC bf16 -----------------------
__global__ void fill_xpad(const float* __restrict__ x, __hip_bfloat16* __restrict__ xp) {
  __shared__ __hip_bfloat16 tile[32][72];   // [x-pos][channel], padded stride
  int t = threadIdx.x;
  int r = blockIdx.x;       // 0..2047 : b*1024 + z*32 + y
  int cg = blockIdx.y;      // 0..5 : channel group of 64
  int b = r >> 10, zy = r & 1023, z = zy >> 5, y = zy & 31;
  const float* src = x + (((size_t)(b*384 + cg*64)) << 15) + zy*32;
#pragma unroll
  for (int p = 0; p < 2; ++p) {
    int chr = p*32 + (t >> 3), part = t & 7;
    float4 v = *(const float4*)(src + (((size_t)chr) << 15) + part*4);
    tile[part*4+0][chr] = __float2bfloat16(v.x);
    tile[part*4+1][chr] = __float2bfloat16(v.y);
    tile[part*4+2][chr] = __float2bfloat16(v.z);
    tile[part*4+3][chr] = __float2bfloat16(v.w);
  }
  __syncthreads();
  int pos = t >> 3, pc = t & 7;
  size_t vox = ((size_t)(b*34 + z + 1)*34 + (y + 1))*34 + (pos + 1);
  short8v val = *(const short8v*)&tile[pos][pc*8];
  *(short8v*)((short*)xp + vox*384 + cg*64 + pc*8) = val;
}

// ---------------- implicit-GEMM conv, 128x128 tile, m97 structure -----------
// src: padded NDHWC bf16 [2*34^3][384]; cw: [384][27][384] bf16
// MODE 0: h = leaky(conv+bias) -> bf16 padded buffer
// MODE 1: out = leaky(conv+bias+resid) -> fp32 d_out (NCDHW)
template <int MODE>
__global__ void gconv(const __hip_bfloat16* __restrict__ src,
                      const __hip_bfloat16* __restrict__ cw,
                      const float* __restrict__ bias,
                      const float* __restrict__ resid,
                      __hip_bfloat16* __restrict__ hout,
                      float* __restrict__ out) {
  __shared__ __align__(16) char lds[16384];   // A: [128][32] bf16 | B: [128][32] bf16
  const int tid  = threadIdx.x;
  const int lane = tid & 63, wid = tid >> 6;
  const int lrow = lane & 15, lq = lane >> 4;
  const int tm = blockIdx.x;          // 512 position tiles
  const int tn = blockIdx.y;          // 3 oc tiles
  const int ocb = tn * 128;
  const int pbase = tm * 128;
  const int b  = pbase >> 15;
  const int zy = (pbase & 32767) >> 5;
  const int z = zy >> 5, y0 = zy & 31;    // y0 multiple of 4

  f32x4 acc[4][4] = {};

  // staging chunk geometry: 1024 x 16B chunks per K-step (A 512 | B 512)
  const int arow0 = tid >> 2, apart = (tid & 3) * 16;
  const int arow1 = arow0 + 64;
  const char* srcB = (const char*)src;
  const char* cwB  = (const char*)cw;
  const int bb0 = (ocb + arow0) * 20736 + apart;  // 20736 = 27*384*2
  const int bb1 = (ocb + arow1) * 20736 + apart;
  const int ay0 = y0 + (arow0 >> 5), ay1 = y0 + (arow1 >> 5);
  const int ax  = arow0 & 31;
  char* ldsw = lds + wid*1024;

  for (int off = 0; off < 27; ++off) {
    const int kz = off/9, kyx = off - kz*9, ky = kyx/3, kx = kyx - ky*3;
    const int a0 = (((b*34 + z + kz)*34 + (ay0 + ky))*34 + ax + kx) * 768 + apart;
    const int a1 = (((b*34 + z + kz)*34 + (ay1 + ky))*34 + ax + kx) * 768 + apart;
    const int bo = off * 768;
    for (int ic = 0; ic < 12; ++ic) {
      const int icb = ic * 64;
      gload16(srcB + a0 + icb,       ldsw);
      gload16(srcB + a1 + icb,       ldsw + 4096);
      gload16(cwB + bb0 + bo + icb,  ldsw + 8192);
      gload16(cwB + bb1 + bo + icb,  ldsw + 12288);
      __syncthreads();
      bf16x8 af[4], bfr[4];
#pragma unroll
      for (int mi = 0; mi < 4; ++mi) {
        int rr = (wid >> 1)*64 + mi*16 + lrow;
        af[mi] = *(const bf16x8*)(lds + rr*64 + lq*16);
      }
#pragma unroll
      for (int ni = 0; ni < 4; ++ni) {
        int rc = (wid & 1)*64 + ni*16 + lrow;
        bfr[ni] = *(const bf16x8*)(lds + 8192 + rc*64 + lq*16);
      }
#pragma unroll
      for (int mi = 0; mi < 4; ++mi)
#pragma unroll
        for (int ni = 0; ni < 4; ++ni)
          acc[mi][ni] = __builtin_amdgcn_mfma_f32_16x16x32_bf16(af[mi], bfr[ni], acc[mi][ni], 0, 0, 0);
      __syncthreads();
    }
  }

  // epilogue
  float bias_n[4];
  int oc_n[4];
#pragma unroll
  for (int ni = 0; ni < 4; ++ni) {
    int oc = ocb + (wid & 1)*64 + ni*16 + lrow;
    oc_n[ni] = oc;
    bias_n[ni] = bias[oc / 24];
  }
  if (MODE == 0) {
    const int voxb = ((b*34 + z + 1)*34 + (y0 + 1))*34 + 1;
#pragma unroll
    for (int mi = 0; mi < 4; ++mi) {
#pragma unroll
      for (int e = 0; e < 4; ++e) {
        int rr = (wid >> 1)*64 + mi*16 + lq*4 + e;
        int vox = voxb + (rr >> 5)*34 + (rr & 31);
        __hip_bfloat16* dst = hout + (size_t)vox*384;
#pragma unroll
        for (int ni = 0; ni < 4; ++ni) {
          float v = acc[mi][ni][e] + bias_n[ni];
          v = v >= 0.f ? v : 0.01f*v;
          dst[oc_n[ni]] = __float2bfloat16(v);
        }
      }
    }
  } else {
    const int zyx0 = pbase & 32767;
#pragma unroll
    for (int mi = 0; mi < 4; ++mi) {
      int rrb = (wid >> 1)*64 + mi*16 + lq*4;
#pragma unroll
      for (int ni = 0; ni < 4; ++ni) {
        size_t ofs = (((size_t)(b*384 + oc_n[ni])) << 15) + zyx0 + rrb;
        float4 res = *(const float4*)(resid + ofs);
        float rv[4] = {res.x, res.y, res.z, res.w};
        float ov[4];
#pragma unroll
        for (int e = 0; e < 4; ++e) {
          float v = acc[mi][ni][e] + bias_n[ni] + rv[e];
          ov[e] = v >= 0.f ? v : 0.01f*v;
        }
        float4 o4 = make_float4(ov[0], ov[1], ov[2], ov[3]);
        *(float4*)(out + ofs) = o4;
      }
    }
  }
}

extern "C" void kernel_launch(void* const* d_in, const int* in_sizes, int n_in,
                              void* d_out, int out_size, void* d_ws, size_t ws_size,
                              hipStream_t stream) {
  const float* x   = (const float*)d_in[0];
  const float* w1  = (const float*)d_in[1];
  const float* rw1 = (const float*)d_in[2];
  const float* b1  = (const float*)d_in[3];
  const float* w2  = (const float*)d_in[4];
  const float* rw2 = (const float*)d_in[5];
  const float* b2  = (const float*)d_in[6];
  float* out = (float*)d_out;

  char* ws = (char*)d_ws;
  // layout: tables | cw1 (8MB) | cw2 (8MB) | x_pad (57.6MB) | h_pad (57.6MB)
  int* shiftT = (int*)ws;                                   // 576 ints
  int* rotT   = (int*)(ws + 2304);                          // 648 ints
  const size_t CW_BYTES  = (size_t)384*27*384*2;            // 7,962,624
  const size_t PAD_BYTES = (size_t)2*34*34*34*384*2;        // 60,370,944
  __hip_bfloat16* cw1  = (__hip_bfloat16*)(ws + 8192);
  __hip_bfloat16* cw2  = (__hip_bfloat16*)(ws + 8192 + CW_BYTES);
  __hip_bfloat16* xpad = (__hip_bfloat16*)(ws + 8192 + 2*CW_BYTES);
  __hip_bfloat16* hpad = (__hip_bfloat16*)(ws + 8192 + 2*CW_BYTES + PAD_BYTES);

  hipMemsetAsync(xpad, 0, PAD_BYTES, stream);
  hipMemsetAsync(hpad, 0, PAD_BYTES, stream);
  build_tables<<<1, 64, 0, stream>>>(shiftT, rotT);
  prep_weights<<<(384*27*384 + 255)/256, 256, 0, stream>>>(w1, rw1, shiftT, rotT, cw1);
  prep_weights<<<(384*27*384 + 255)/256, 256, 0, stream>>>(w2, rw2, shiftT, rotT, cw2);
  fill_xpad<<<dim3(2048, 6), 256, 0, stream>>>(x, xpad);
  gconv<0><<<dim3(512, 3), 256, 0, stream>>>(xpad, cw1, b1, nullptr, hpad, nullptr);
  gconv<1><<<dim3(512, 3), 256, 0, stream>>>(hpad, cw2, b2, x, nullptr, out);
}

// Round 2
// 1464.665 us; speedup vs baseline: 2.0476x; 2.0476x over previous
//
#include <hip/hip_runtime.h>
#include <hip/hip_bf16.h>
#include <stdint.h>

typedef __bf16 bf16x8 __attribute__((ext_vector_type(8)));
typedef float  f32x4  __attribute__((ext_vector_type(4)));
typedef short  short8v __attribute__((ext_vector_type(8)));

// ---------------- async global->LDS (wave-uniform LDS base + lane*16) -------
__device__ __forceinline__ void gload16(const void* gp, void* lp) {
  __builtin_amdgcn_global_load_lds(
      reinterpret_cast<const __attribute__((address_space(1))) uint32_t*>(
          reinterpret_cast<uintptr_t>(gp)),
      reinterpret_cast<__attribute__((address_space(3))) uint32_t*>(
          (uintptr_t)(uint32_t)reinterpret_cast<uintptr_t>(lp)),
      16, 0, 0);
}

// ---------------- octahedral group tables, parallel (1 thread / entry) ------
// 576 SHIFT entries + 648 ROT entries; each thread rebuilds the 24 group
// matrices locally (48 cheap iterations) then computes one table entry.
__global__ void build_tables(int* __restrict__ shift, int* __restrict__ rot) {
  int tid = blockIdx.x * blockDim.x + threadIdx.x;
  if (tid >= 576 + 648) return;
  const int perms[6][3] = {{0,1,2},{0,2,1},{1,0,2},{1,2,0},{2,0,1},{2,1,0}};
  const int psign[6] = {1,-1,-1,1,1,-1};
  int mats[24][3][3];
  int nm = 0;
  for (int pi = 0; pi < 6; ++pi)
    for (int sb = 0; sb < 8; ++sb) {
      int s0 = (sb&4)?-1:1, s1 = (sb&2)?-1:1, s2 = (sb&1)?-1:1;
      if (psign[pi]*s0*s1*s2 != 1) continue;
      int sg[3] = {s0,s1,s2};
      for (int i = 0; i < 3; ++i)
        for (int j = 0; j < 3; ++j)
          mats[nm][i][j] = (j == perms[pi][i]) ? sg[i] : 0;
      ++nm;
    }
  if (tid < 576) {
    // SHIFT[g][h] = index of mats[g]^T @ mats[h]
    int g = tid / 24, h = tid % 24;
    int P[3][3];
    for (int i = 0; i < 3; ++i)
      for (int j = 0; j < 3; ++j) {
        int v = 0;
        for (int k = 0; k < 3; ++k) v += mats[g][k][i]*mats[h][k][j];
        P[i][j] = v;
      }
    int id = -1;
    for (int m = 0; m < 24 && id < 0; ++m) {
      bool eq = true;
      for (int i = 0; i < 3; ++i)
        for (int j = 0; j < 3; ++j) eq = eq && (mats[m][i][j] == P[i][j]);
      if (eq) id = m;
    }
    shift[tid] = id;
  } else {
    // ROT[g][dst]: src_j = sum_i (v_i-1)*M[i][j] + 1
    int r = tid - 576;
    int g = r / 27, vox = r % 27;
    int z = vox / 9, y = (vox / 3) % 3, x = vox % 3;
    int v[3] = {z-1, y-1, x-1}, s[3];
    for (int j = 0; j < 3; ++j) {
      int a = 0;
      for (int i = 0; i < 3; ++i) a += v[i]*mats[g][i][j];
      s[j] = a + 1;
    }
    rot[g*27 + vox] = (s[0]*3 + s[1])*3 + s[2];
  }
}

// ---------------- weight fold: cw[oc][s][icf] bf16 --------------------------
__global__ void prep_weights(const float* __restrict__ w, const float* __restrict__ rw,
                             const int* __restrict__ shift, const int* __restrict__ rot,
                             __hip_bfloat16* __restrict__ cw) {
  int idx = blockIdx.x*256 + threadIdx.x;
  if (idx >= 384*27*384) return;
  int icf = idx % 384;
  int s   = (idx / 384) % 27;
  int oc  = idx / (384*27);
  int i = icf / 24, h = icf - i*24;
  int o = oc  / 24, g = oc  - o*24;
  int gg = shift[g*24 + h];
  int ss = rot[g*27 + s];
  float v = rw[g]      * w[((o*16 + i)*24 + gg)*27 + ss]
          + rw[24 + g] * w[(((16 + o)*16 + i)*24 + gg)*27 + ss];
  cw[idx] = __float2bfloat16(v);
}

// ---------------- x (NCDHW fp32) -> padded NDHWC bf16 -----------------------
__global__ void fill_xpad(const float* __restrict__ x, __hip_bfloat16* __restrict__ xp) {
  __shared__ __hip_bfloat16 tile[32][72];   // [x-pos][channel], padded stride
  int t = threadIdx.x;
  int r = blockIdx.x;       // 0..2047 : b*1024 + z*32 + y
  int cg = blockIdx.y;      // 0..5 : channel group of 64
  int b = r >> 10, zy = r & 1023, z = zy >> 5, y = zy & 31;
  const float* src = x + (((size_t)(b*384 + cg*64)) << 15) + zy*32;
#pragma unroll
  for (int p = 0; p < 2; ++p) {
    int chr = p*32 + (t >> 3), part = t & 7;
    float4 v = *(const float4*)(src + (((size_t)chr) << 15) + part*4);
    tile[part*4+0][chr] = __float2bfloat16(v.x);
    tile[part*4+1][chr] = __float2bfloat16(v.y);
    tile[part*4+2][chr] = __float2bfloat16(v.z);
    tile[part*4+3][chr] = __float2bfloat16(v.w);
  }
  __syncthreads();
  int pos = t >> 3, pc = t & 7;
  size_t vox = ((size_t)(b*34 + z + 1)*34 + (y + 1))*34 + (pos + 1);
  short8v val = *(const short8v*)&tile[pos][pc*8];
  *(short8v*)((short*)xp + vox*384 + cg*64 + pc*8) = val;
}

// ---------------- implicit-GEMM conv, 128x128 tile, m97 structure -----------
// src: padded NDHWC bf16 [2*34^3][384]; cw: [384][27][384] bf16
// MODE 0: h = leaky(conv+bias) -> bf16 padded buffer
// MODE 1: out = leaky(conv+bias+resid) -> fp32 d_out (NCDHW)
template <int MODE>
__global__ void gconv(const __hip_bfloat16* __restrict__ src,
                      const __hip_bfloat16* __restrict__ cw,
                      const float* __restrict__ bias,
                      const float* __restrict__ resid,
                      __hip_bfloat16* __restrict__ hout,
                      float* __restrict__ out) {
  __shared__ __align__(16) char lds[16384];   // A: [128][32] bf16 | B: [128][32] bf16
  const int tid  = threadIdx.x;
  const int lane = tid & 63, wid = tid >> 6;
  const int lrow = lane & 15, lq = lane >> 4;
  const int tm = blockIdx.x;          // 512 position tiles
  const int tn = blockIdx.y;          // 3 oc tiles
  const int ocb = tn * 128;
  const int pbase = tm * 128;
  const int b  = pbase >> 15;
  const int zy = (pbase & 32767) >> 5;
  const int z = zy >> 5, y0 = zy & 31;    // y0 multiple of 4

  f32x4 acc[4][4] = {};

  // staging chunk geometry: 1024 x 16B chunks per K-step (A 512 | B 512)
  const int arow0 = tid >> 2, apart = (tid & 3) * 16;
  const int arow1 = arow0 + 64;
  const char* srcB = (const char*)src;
  const char* cwB  = (const char*)cw;
  const int bb0 = (ocb + arow0) * 20736 + apart;  // 20736 = 27*384*2
  const int bb1 = (ocb + arow1) * 20736 + apart;
  const int ay0 = y0 + (arow0 >> 5), ay1 = y0 + (arow1 >> 5);
  const int ax  = arow0 & 31;
  char* ldsw = lds + wid*1024;

  for (int off = 0; off < 27; ++off) {
    const int kz = off/9, kyx = off - kz*9, ky = kyx/3, kx = kyx - ky*3;
    const int a0 = (((b*34 + z + kz)*34 + (ay0 + ky))*34 + ax + kx) * 768 + apart;
    const int a1 = (((b*34 + z + kz)*34 + (ay1 + ky))*34 + ax + kx) * 768 + apart;
    const int bo = off * 768;
    for (int ic = 0; ic < 12; ++ic) {
      const int icb = ic * 64;
      gload16(srcB + a0 + icb,       ldsw);
      gload16(srcB + a1 + icb,       ldsw + 4096);
      gload16(cwB + bb0 + bo + icb,  ldsw + 8192);
      gload16(cwB + bb1 + bo + icb,  ldsw + 12288);
      __syncthreads();
      bf16x8 af[4], bfr[4];
#pragma unroll
      for (int mi = 0; mi < 4; ++mi) {
        int rr = (wid >> 1)*64 + mi*16 + lrow;
        af[mi] = *(const bf16x8*)(lds + rr*64 + lq*16);
      }
#pragma unroll
      for (int ni = 0; ni < 4; ++ni) {
        int rc = (wid & 1)*64 + ni*16 + lrow;
        bfr[ni] = *(const bf16x8*)(lds + 8192 + rc*64 + lq*16);
      }
#pragma unroll
      for (int mi = 0; mi < 4; ++mi)
#pragma unroll
        for (int ni = 0; ni < 4; ++ni)
          acc[mi][ni] = __builtin_amdgcn_mfma_f32_16x16x32_bf16(af[mi], bfr[ni], acc[mi][ni], 0, 0, 0);
      __syncthreads();
    }
  }

  // epilogue
  float bias_n[4];
  int oc_n[4];
#pragma unroll
  for (int ni = 0; ni < 4; ++ni) {
    int oc = ocb + (wid & 1)*64 + ni*16 + lrow;
    oc_n[ni] = oc;
    bias_n[ni] = bias[oc / 24];
  }
  if (MODE == 0) {
    const int voxb = ((b*34 + z + 1)*34 + (y0 + 1))*34 + 1;
#pragma unroll
    for (int mi = 0; mi < 4; ++mi) {
#pragma unroll
      for (int e = 0; e < 4; ++e) {
        int rr = (wid >> 1)*64 + mi*16 + lq*4 + e;
        int vox = voxb + (rr >> 5)*34 + (rr & 31);
        __hip_bfloat16* dst = hout + (size_t)vox*384;
#pragma unroll
        for (int ni = 0; ni < 4; ++ni) {
          float v = acc[mi][ni][e] + bias_n[ni];
          v = v >= 0.f ? v : 0.01f*v;
          dst[oc_n[ni]] = __float2bfloat16(v);
        }
      }
    }
  } else {
    const int zyx0 = pbase & 32767;
#pragma unroll
    for (int mi = 0; mi < 4; ++mi) {
      int rrb = (wid >> 1)*64 + mi*16 + lq*4;
#pragma unroll
      for (int ni = 0; ni < 4; ++ni) {
        size_t ofs = (((size_t)(b*384 + oc_n[ni])) << 15) + zyx0 + rrb;
        float4 res = *(const float4*)(resid + ofs);
        float rv[4] = {res.x, res.y, res.z, res.w};
        float ov[4];
#pragma unroll
        for (int e = 0; e < 4; ++e) {
          float v = acc[mi][ni][e] + bias_n[ni] + rv[e];
          ov[e] = v >= 0.f ? v : 0.01f*v;
        }
        float4 o4 = make_float4(ov[0], ov[1], ov[2], ov[3]);
        *(float4*)(out + ofs) = o4;
      }
    }
  }
}

extern "C" void kernel_launch(void* const* d_in, const int* in_sizes, int n_in,
                              void* d_out, int out_size, void* d_ws, size_t ws_size,
                              hipStream_t stream) {
  const float* x   = (const float*)d_in[0];
  const float* w1  = (const float*)d_in[1];
  const float* rw1 = (const float*)d_in[2];
  const float* b1  = (const float*)d_in[3];
  const float* w2  = (const float*)d_in[4];
  const float* rw2 = (const float*)d_in[5];
  const float* b2  = (const float*)d_in[6];
  float* out = (float*)d_out;

  char* ws = (char*)d_ws;
  // layout: tables | cw1 (8MB) | cw2 (8MB) | x_pad (57.6MB) | h_pad (57.6MB)
  int* shiftT = (int*)ws;                                   // 576 ints
  int* rotT   = (int*)(ws + 2304);                          // 648 ints
  const size_t CW_BYTES  = (size_t)384*27*384*2;            // 7,962,624
  const size_t PAD_BYTES = (size_t)2*34*34*34*384*2;        // 60,370,944
  __hip_bfloat16* cw1  = (__hip_bfloat16*)(ws + 8192);
  __hip_bfloat16* cw2  = (__hip_bfloat16*)(ws + 8192 + CW_BYTES);
  __hip_bfloat16* xpad = (__hip_bfloat16*)(ws + 8192 + 2*CW_BYTES);
  __hip_bfloat16* hpad = (__hip_bfloat16*)(ws + 8192 + 2*CW_BYTES + PAD_BYTES);

  hipMemsetAsync(xpad, 0, PAD_BYTES, stream);
  hipMemsetAsync(hpad, 0, PAD_BYTES, stream);
  build_tables<<<5, 256, 0, stream>>>(shiftT, rotT);
  prep_weights<<<(384*27*384 + 255)/256, 256, 0, stream>>>(w1, rw1, shiftT, rotT, cw1);
  prep_weights<<<(384*27*384 + 255)/256, 256, 0, stream>>>(w2, rw2, shiftT, rotT, cw2);
  fill_xpad<<<dim3(2048, 6), 256, 0, stream>>>(x, xpad);
  gconv<0><<<dim3(512, 3), 256, 0, stream>>>(xpad, cw1, b1, nullptr, hpad, nullptr);
  gconv<1><<<dim3(512, 3), 256, 0, stream>>>(hpad, cw2, b2, x, nullptr, out);
}

// Round 3
// 1323.463 us; speedup vs baseline: 2.2660x; 1.1067x over previous
//
#include <hip/hip_runtime.h>
#include <hip/hip_bf16.h>
#include <stdint.h>

typedef __bf16 bf16x8 __attribute__((ext_vector_type(8)));
typedef float  f32x4  __attribute__((ext_vector_type(4)));
typedef short  short8v __attribute__((ext_vector_type(8)));

// ---------------- async global->LDS (wave-uniform LDS base + lane*16) -------
__device__ __forceinline__ void gload16(const void* gp, void* lp) {
  __builtin_amdgcn_global_load_lds(
      reinterpret_cast<const __attribute__((address_space(1))) uint32_t*>(
          reinterpret_cast<uintptr_t>(gp)),
      reinterpret_cast<__attribute__((address_space(3))) uint32_t*>(
          (uintptr_t)(uint32_t)reinterpret_cast<uintptr_t>(lp)),
      16, 0, 0);
}

// ---------------- octahedral group tables, parallel (1 thread / entry) ------
__global__ void build_tables(int* __restrict__ shift, int* __restrict__ rot) {
  int tid = blockIdx.x * blockDim.x + threadIdx.x;
  if (tid >= 576 + 648) return;
  const int perms[6][3] = {{0,1,2},{0,2,1},{1,0,2},{1,2,0},{2,0,1},{2,1,0}};
  const int psign[6] = {1,-1,-1,1,1,-1};
  int mats[24][3][3];
  int nm = 0;
  for (int pi = 0; pi < 6; ++pi)
    for (int sb = 0; sb < 8; ++sb) {
      int s0 = (sb&4)?-1:1, s1 = (sb&2)?-1:1, s2 = (sb&1)?-1:1;
      if (psign[pi]*s0*s1*s2 != 1) continue;
      int sg[3] = {s0,s1,s2};
      for (int i = 0; i < 3; ++i)
        for (int j = 0; j < 3; ++j)
          mats[nm][i][j] = (j == perms[pi][i]) ? sg[i] : 0;
      ++nm;
    }
  if (tid < 576) {
    int g = tid / 24, h = tid % 24;
    int P[3][3];
    for (int i = 0; i < 3; ++i)
      for (int j = 0; j < 3; ++j) {
        int v = 0;
        for (int k = 0; k < 3; ++k) v += mats[g][k][i]*mats[h][k][j];
        P[i][j] = v;
      }
    int id = -1;
    for (int m = 0; m < 24 && id < 0; ++m) {
      bool eq = true;
      for (int i = 0; i < 3; ++i)
        for (int j = 0; j < 3; ++j) eq = eq && (mats[m][i][j] == P[i][j]);
      if (eq) id = m;
    }
    shift[tid] = id;
  } else {
    int r = tid - 576;
    int g = r / 27, vox = r % 27;
    int z = vox / 9, y = (vox / 3) % 3, x = vox % 3;
    int v[3] = {z-1, y-1, x-1}, s[3];
    for (int j = 0; j < 3; ++j) {
      int a = 0;
      for (int i = 0; i < 3; ++i) a += v[i]*mats[g][i][j];
      s[j] = a + 1;
    }
    rot[g*27 + vox] = (s[0]*3 + s[1])*3 + s[2];
  }
}

// ---------------- weight fold: cw[oc][s][icf] bf16 --------------------------
__global__ void prep_weights(const float* __restrict__ w, const float* __restrict__ rw,
                             const int* __restrict__ shift, const int* __restrict__ rot,
                             __hip_bfloat16* __restrict__ cw) {
  int idx = blockIdx.x*256 + threadIdx.x;
  if (idx >= 384*27*384) return;
  int icf = idx % 384;
  int s   = (idx / 384) % 27;
  int oc  = idx / (384*27);
  int i = icf / 24, h = icf - i*24;
  int o = oc  / 24, g = oc  - o*24;
  int gg = shift[g*24 + h];
  int ss = rot[g*27 + s];
  float v = rw[g]      * w[((o*16 + i)*24 + gg)*27 + ss]
          + rw[24 + g] * w[(((16 + o)*16 + i)*24 + gg)*27 + ss];
  cw[idx] = __float2bfloat16(v);
}

// ---------------- x (NCDHW fp32) -> padded NDHWC bf16 -----------------------
__global__ void fill_xpad(const float* __restrict__ x, __hip_bfloat16* __restrict__ xp) {
  __shared__ __hip_bfloat16 tile[32][72];
  int t = threadIdx.x;
  int r = blockIdx.x;       // b*1024 + z*32 + y
  int cg = blockIdx.y;      // channel group of 64
  int b = r >> 10, zy = r & 1023, z = zy >> 5, y = zy & 31;
  const float* src = x + (((size_t)(b*384 + cg*64)) << 15) + zy*32;
#pragma unroll
  for (int p = 0; p < 2; ++p) {
    int chr = p*32 + (t >> 3), part = t & 7;
    float4 v = *(const float4*)(src + (((size_t)chr) << 15) + part*4);
    tile[part*4+0][chr] = __float2bfloat16(v.x);
    tile[part*4+1][chr] = __float2bfloat16(v.y);
    tile[part*4+2][chr] = __float2bfloat16(v.z);
    tile[part*4+3][chr] = __float2bfloat16(v.w);
  }
  __syncthreads();
  int pos = t >> 3, pc = t & 7;
  size_t vox = ((size_t)(b*34 + z + 1)*34 + (y + 1))*34 + (pos + 1);
  short8v val = *(const short8v*)&tile[pos][pc*8];
  *(short8v*)((short*)xp + vox*384 + cg*64 + pc*8) = val;
}

// ---------------- implicit-GEMM conv: 128x128 tile, dbuf, T2 swizzle --------
// src: padded NDHWC bf16 [2*34^3][384]; cw: [384][27][384] bf16
// MODE 0: h = leaky(conv+bias) -> bf16 padded buffer
// MODE 1: out = leaky(conv+bias+resid) -> fp32 d_out (NCDHW)
template <int MODE>
__global__ void gconv(const __hip_bfloat16* __restrict__ src,
                      const __hip_bfloat16* __restrict__ cw,
                      const float* __restrict__ bias,
                      const float* __restrict__ resid,
                      __hip_bfloat16* __restrict__ hout,
                      float* __restrict__ out) {
  __shared__ __align__(16) char lds[32768];   // 2 bufs x (A 8K | B 8K)
  const int tid  = threadIdx.x;
  const int lane = tid & 63, wid = tid >> 6;
  const int lrow = lane & 15, lq = lane >> 4;
  // chunked XCD swizzle: 1536 blocks = 8 XCDs x 192; tn-fastest within chunk
  const int bid = blockIdx.x;
  const int swz = (bid & 7) * 192 + (bid >> 3);
  const int tm = swz / 3;
  const int tn = swz - tm * 3;
  const int ocb = tn * 128;
  const int pbase = tm * 128;
  const int b  = pbase >> 15;
  const int zy = (pbase & 32767) >> 5;
  const int z = zy >> 5, y0 = zy & 31;    // y0 multiple of 4

  f32x4 acc[4][4] = {};

  // staging geometry: per K-step 1024 x 16B chunks (A 512 | B 512)
  // T2 swizzle (both sides): physical slot s holds global part s ^ ((row>>1)&3)
  const int arow0 = tid >> 2;
  const int arow1 = arow0 + 64;                       // (row>>1)&3 identical for +64
  const int apart_sw = (((tid & 3) ^ ((tid >> 3) & 3))) * 16;
  const char* srcB = (const char*)src;
  const char* cwB  = (const char*)cw;
  const int bb0 = (ocb + arow0) * 20736 + apart_sw;   // 20736 = 27*384*2
  const int bb1 = (ocb + arow1) * 20736 + apart_sw;
  const int ay0 = y0 + (arow0 >> 5), ay1 = y0 + (arow1 >> 5);
  const int ax  = arow0 & 31;
  const int voxb0 = (((b*34 + z)*34 + ay0)*34 + ax) * 768 + apart_sw;
  const int voxb1 = (((b*34 + z)*34 + ay1)*34 + ax) * 768 + apart_sw;
  const int ldsw = wid * 1024;

  auto stage = [&](int buf, int tapoff, int icb, int tb) {
    char* A = lds + buf*16384 + ldsw;
    gload16(srcB + voxb0 + tapoff + icb, A);
    gload16(srcB + voxb1 + tapoff + icb, A + 4096);
    gload16(cwB  + bb0   + tb,           A + 8192);
    gload16(cwB  + bb1   + tb,           A + 12288);
  };

  stage(0, 0, 0, 0);
  __syncthreads();

  const int slot = (lq ^ ((lrow >> 1) & 3)) * 16;     // read-side swizzle
  const int arow_rd = (wid >> 1) * 64 + lrow;
  const int brow_rd = (wid & 1) * 64 + lrow;
  int offs = 0, ics = 1;       // indices of next K-step to stage (flat t=1)
  int cur = 0;
  for (int t = 0; t < 324; ++t) {
    if (t < 323) {
      int kz = offs / 9, kyx = offs - kz * 9, ky = kyx / 3, kx = kyx - ky * 3;
      int tapoff = (kz * 1156 + ky * 34 + kx) * 768;
      stage(cur ^ 1, tapoff, ics * 64, (t + 1) * 64);
      if (++ics == 12) { ics = 0; ++offs; }
    }
    const char* Ab = lds + cur * 16384;
    bf16x8 af[4], bfr[4];
#pragma unroll
    for (int mi = 0; mi < 4; ++mi)
      af[mi] = *(const bf16x8*)(Ab + (arow_rd + mi*16) * 64 + slot);
#pragma unroll
    for (int ni = 0; ni < 4; ++ni)
      bfr[ni] = *(const bf16x8*)(Ab + 8192 + (brow_rd + ni*16) * 64 + slot);
#pragma unroll
    for (int mi = 0; mi < 4; ++mi)
#pragma unroll
      for (int ni = 0; ni < 4; ++ni)
        acc[mi][ni] = __builtin_amdgcn_mfma_f32_16x16x32_bf16(af[mi], bfr[ni], acc[mi][ni], 0, 0, 0);
    __syncthreads();
    cur ^= 1;
  }

  // epilogue
  float bias_n[4];
  int oc_n[4];
#pragma unroll
  for (int ni = 0; ni < 4; ++ni) {
    int oc = ocb + (wid & 1)*64 + ni*16 + lrow;
    oc_n[ni] = oc;
    bias_n[ni] = bias[oc / 24];
  }
  if (MODE == 0) {
    const int voxb = ((b*34 + z + 1)*34 + (y0 + 1))*34 + 1;
#pragma unroll
    for (int mi = 0; mi < 4; ++mi) {
#pragma unroll
      for (int e = 0; e < 4; ++e) {
        int rr = (wid >> 1)*64 + mi*16 + lq*4 + e;
        int vox = voxb + (rr >> 5)*34 + (rr & 31);
        __hip_bfloat16* dst = hout + (size_t)vox*384;
#pragma unroll
        for (int ni = 0; ni < 4; ++ni) {
          float v = acc[mi][ni][e] + bias_n[ni];
          v = v >= 0.f ? v : 0.01f*v;
          dst[oc_n[ni]] = __float2bfloat16(v);
        }
      }
    }
  } else {
    const int zyx0 = pbase & 32767;
#pragma unroll
    for (int mi = 0; mi < 4; ++mi) {
      int rrb = (wid >> 1)*64 + mi*16 + lq*4;
#pragma unroll
      for (int ni = 0; ni < 4; ++ni) {
        size_t ofs = (((size_t)(b*384 + oc_n[ni])) << 15) + zyx0 + rrb;
        float4 res = *(const float4*)(resid + ofs);
        float rv[4] = {res.x, res.y, res.z, res.w};
        float ov[4];
#pragma unroll
        for (int e = 0; e < 4; ++e) {
          float v = acc[mi][ni][e] + bias_n[ni] + rv[e];
          ov[e] = v >= 0.f ? v : 0.01f*v;
        }
        float4 o4 = make_float4(ov[0], ov[1], ov[2], ov[3]);
        *(float4*)(out + ofs) = o4;
      }
    }
  }
}

extern "C" void kernel_launch(void* const* d_in, const int* in_sizes, int n_in,
                              void* d_out, int out_size, void* d_ws, size_t ws_size,
                              hipStream_t stream) {
  const float* x   = (const float*)d_in[0];
  const float* w1  = (const float*)d_in[1];
  const float* rw1 = (const float*)d_in[2];
  const float* b1  = (const float*)d_in[3];
  const float* w2  = (const float*)d_in[4];
  const float* rw2 = (const float*)d_in[5];
  const float* b2  = (const float*)d_in[6];
  float* out = (float*)d_out;

  char* ws = (char*)d_ws;
  int* shiftT = (int*)ws;
  int* rotT   = (int*)(ws + 2304);
  const size_t CW_BYTES  = (size_t)384*27*384*2;
  const size_t PAD_BYTES = (size_t)2*34*34*34*384*2;
  __hip_bfloat16* cw1  = (__hip_bfloat16*)(ws + 8192);
  __hip_bfloat16* cw2  = (__hip_bfloat16*)(ws + 8192 + CW_BYTES);
  __hip_bfloat16* xpad = (__hip_bfloat16*)(ws + 8192 + 2*CW_BYTES);
  __hip_bfloat16* hpad = (__hip_bfloat16*)(ws + 8192 + 2*CW_BYTES + PAD_BYTES);

  hipMemsetAsync(xpad, 0, PAD_BYTES, stream);
  hipMemsetAsync(hpad, 0, PAD_BYTES, stream);
  build_tables<<<5, 256, 0, stream>>>(shiftT, rotT);
  prep_weights<<<(384*27*384 + 255)/256, 256, 0, stream>>>(w1, rw1, shiftT, rotT, cw1);
  prep_weights<<<(384*27*384 + 255)/256, 256, 0, stream>>>(w2, rw2, shiftT, rotT, cw2);
  fill_xpad<<<dim3(2048, 6), 256, 0, stream>>>(x, xpad);
  gconv<0><<<dim3(1536, 1), 256, 0, stream>>>(xpad, cw1, b1, nullptr, hpad, nullptr);
  gconv<1><<<dim3(1536, 1), 256, 0, stream>>>(hpad, cw2, b2, x, nullptr, out);
}